// Round 7
// baseline (969.876 us; speedup 1.0000x reference)
//
#include <hip/hip_runtime.h>

#define N_NODES 100000
#define N_EDGES 3200000
#define F_IN 256
#define H1 64
#define H2 32
#define C_OUT 1000

// ---- workspace layout (4-byte units) ----
#define OFF_G     0          // float[32]
#define OFF_DINV  64         // float[N]
#define OFF_CNT   100096     // int[N]
#define OFF_HEAD  200128     // int[N]
#define OFF_NODE2 300160     // int2[E] = 6.4M floats (8B-aligned: 300160*4 % 8 == 0)
#define OFF_Y1B   6700160    // ushort[N*64] = 3.2M floats
#define OFF_Y2Q   9900160    // uchar[N*32] = 0.2M floats
// total 10,100,160 * 4B = 40.4 MB

__device__ __forceinline__ unsigned short f2bf(float f) {
    unsigned u = __float_as_uint(f);
    u += 0x7FFFu + ((u >> 16) & 1u);  // RNE
    return (unsigned short)(u >> 16);
}
__device__ __forceinline__ float bf2f(unsigned short s) {
    return __uint_as_float(((unsigned)s) << 16);
}

// fp8 e4m3fn encode, RNE, saturating (finite inputs)
__device__ __forceinline__ unsigned char f2fp8(float x) {
    x = fminf(fmaxf(x, -448.0f), 448.0f);
    unsigned u = __float_as_uint(x);
    unsigned s = (u >> 24) & 0x80u;
    unsigned absu = u & 0x7fffffffu;
    float ax = __uint_as_float(absu);
    if (ax < 0.015625f) {                      // subnormal: q = RNE(ax * 2^9), 0..8
        int q = __float2int_rn(ax * 512.0f);   // q==8 naturally becomes exp=1,man=0
        return (unsigned char)(s | (unsigned)q);
    }
    int e = (int)(absu >> 23) - 127;
    unsigned man = absu & 0x7fffffu;
    unsigned m3 = man >> 20;
    unsigned rem = man & 0xFFFFFu;
    if (rem > 0x80000u || (rem == 0x80000u && (m3 & 1u))) m3++;
    if (m3 == 8u) { m3 = 0u; e++; }
    if (e > 8) return (unsigned char)(s | 0x7Eu);   // 448
    return (unsigned char)(s | ((unsigned)(e + 7) << 3) | m3);
}

// fp8 e4m3fn decode value for LUT slot t (0..255)
__device__ __forceinline__ float fp8lut_val(int t) {
    int ex = (t >> 3) & 15, man = t & 7;
    int base = ex ? (8 + man) : man;
    float v = ldexpf((float)base, (ex ? ex : 1) - 10);
    return (t & 0x80) ? -v : v;
}

// ---------------- init: head=-1, cnt=0, g=0 ----------------
__global__ void k_init(int* __restrict__ head, int* __restrict__ cnt,
                       float* __restrict__ g) {
    int i = blockIdx.x * 256 + threadIdx.x;
    if (i < N_NODES) { head[i] = -1; cnt[i] = 0; }
    if (blockIdx.x == 0 && threadIdx.x < H2) g[threadIdx.x] = 0.0f;
}

// ---------------- build: linked list + degree histogram, packed (src,next) ----------------
__global__ void k_build(const int* __restrict__ src, const int* __restrict__ dst,
                        int* __restrict__ head, int* __restrict__ cnt,
                        int2* __restrict__ node2) {
    int e = blockIdx.x * 256 + threadIdx.x;
    if (e < N_EDGES) {
        int d = dst[e];
        int s = src[e];
        int prev = atomicExch(&head[d], e);
        node2[e] = make_int2(s, prev);   // coalesced 8B write
        atomicAdd(&cnt[d], 1);
    }
}

__global__ void k_dinv(const int* __restrict__ cnt, float* __restrict__ dinv) {
    int n = blockIdx.x * 256 + threadIdx.x;
    if (n < N_NODES) dinv[n] = rsqrtf(1.0f + (float)cnt[n]);
}

// ---------------- layer-1 GEMM, 2-node register blocking, bf16 output ----------------
__global__ __launch_bounds__(256) void k_gemm1(const float* __restrict__ x,
                                               const float* __restrict__ W1,
                                               const float* __restrict__ dinv,
                                               unsigned short* __restrict__ y1b) {
    __shared__ float w[F_IN][H1];  // 64 KB
    {
        const float4* Wv = (const float4*)W1;
        float4* wv = (float4*)&w[0][0];
        for (int i = threadIdx.x; i < F_IN * H1 / 4; i += 256) wv[i] = Wv[i];
    }
    __syncthreads();
    int n0 = blockIdx.x * 512 + threadIdx.x;
    int n1 = n0 + 256;
    bool v0 = n0 < N_NODES, v1 = n1 < N_NODES;
    int n0c = v0 ? n0 : 0, n1c = v1 ? n1 : 0;

    float acc0[H1], acc1[H1];
#pragma unroll
    for (int j = 0; j < H1; j++) { acc0[j] = 0.0f; acc1[j] = 0.0f; }

    const float4* xr0 = (const float4*)(x + (size_t)n0c * F_IN);
    const float4* xr1 = (const float4*)(x + (size_t)n1c * F_IN);
#pragma unroll 2
    for (int k0 = 0; k0 < F_IN / 4; k0++) {
        float4 xa = xr0[k0];
        float4 xb = xr1[k0];
#pragma unroll
        for (int d = 0; d < 4; d++) {
            float xv0 = (d == 0 ? xa.x : d == 1 ? xa.y : d == 2 ? xa.z : xa.w);
            float xv1 = (d == 0 ? xb.x : d == 1 ? xb.y : d == 2 ? xb.z : xb.w);
            const float4* wr = (const float4*)&w[k0 * 4 + d][0];
#pragma unroll
            for (int j4 = 0; j4 < H1 / 4; j4++) {
                float4 wq = wr[j4];
                acc0[j4 * 4 + 0] += xv0 * wq.x;
                acc0[j4 * 4 + 1] += xv0 * wq.y;
                acc0[j4 * 4 + 2] += xv0 * wq.z;
                acc0[j4 * 4 + 3] += xv0 * wq.w;
                acc1[j4 * 4 + 0] += xv1 * wq.x;
                acc1[j4 * 4 + 1] += xv1 * wq.y;
                acc1[j4 * 4 + 2] += xv1 * wq.z;
                acc1[j4 * 4 + 3] += xv1 * wq.w;
            }
        }
    }
    if (v0) {
        float dv = dinv[n0];
        unsigned pk[H1 / 2];
#pragma unroll
        for (int j2 = 0; j2 < H1 / 2; j2++) {
            unsigned lo = f2bf(acc0[2 * j2] * dv);
            unsigned hi = f2bf(acc0[2 * j2 + 1] * dv);
            pk[j2] = lo | (hi << 16);
        }
        uint4* o = (uint4*)(y1b + (size_t)n0 * H1);
#pragma unroll
        for (int q = 0; q < H1 / 8; q++)
            o[q] = make_uint4(pk[q * 4], pk[q * 4 + 1], pk[q * 4 + 2], pk[q * 4 + 3]);
    }
    if (v1) {
        float dv = dinv[n1];
        unsigned pk[H1 / 2];
#pragma unroll
        for (int j2 = 0; j2 < H1 / 2; j2++) {
            unsigned lo = f2bf(acc1[2 * j2] * dv);
            unsigned hi = f2bf(acc1[2 * j2 + 1] * dv);
            pk[j2] = lo | (hi << 16);
        }
        uint4* o = (uint4*)(y1b + (size_t)n1 * H1);
#pragma unroll
        for (int q = 0; q < H1 / 8; q++)
            o[q] = make_uint4(pk[q * 4], pk[q * 4 + 1], pk[q * 4 + 2], pk[q * 4 + 3]);
    }
}

// ---------------- fused: chain-gather layer1 + ReLU + GEMM2 -> y2 (fp8) ----------------
// block=256 = 4 waves; each wave walks TWO chains via packed int2 (1 line/hop).
__global__ __launch_bounds__(256) void k_agg1_gemm2(const unsigned short* __restrict__ y1b,
                                                    const int* __restrict__ head,
                                                    const int2* __restrict__ node2,
                                                    const float* __restrict__ dinv,
                                                    const float* __restrict__ b1,
                                                    const float* __restrict__ W2,
                                                    unsigned char* __restrict__ y2q) {
    __shared__ float w2s[H1][H2];  // 8 KB
    __shared__ float hbuf[8][H1];  // 2 KB
    {
        const float4* Wv = (const float4*)W2;
        float4* wv = (float4*)&w2s[0][0];
        for (int i = threadIdx.x; i < H1 * H2 / 4; i += 256) wv[i] = Wv[i];
    }

    const int t = threadIdx.x;
    const int wid = t >> 6;
    const int c = t & 63;
    const int n0 = blockIdx.x * 8 + wid * 2;
    const int n1 = n0 + 1;

    float a0 = bf2f(y1b[(size_t)n0 * H1 + c]);  // self-loop
    float a1 = bf2f(y1b[(size_t)n1 * H1 + c]);
    int e0 = head[n0], e1 = head[n1];
    while (e0 >= 0 && e1 >= 0) {
        int2 v0 = node2[e0];
        int2 v1 = node2[e1];
        a0 += bf2f(y1b[(size_t)v0.x * H1 + c]);
        a1 += bf2f(y1b[(size_t)v1.x * H1 + c]);
        e0 = v0.y; e1 = v1.y;
    }
    while (e0 >= 0) {
        int2 v0 = node2[e0];
        a0 += bf2f(y1b[(size_t)v0.x * H1 + c]);
        e0 = v0.y;
    }
    while (e1 >= 0) {
        int2 v1 = node2[e1];
        a1 += bf2f(y1b[(size_t)v1.x * H1 + c]);
        e1 = v1.y;
    }
    float h0 = dinv[n0] * a0 + b1[c];
    float h1v = dinv[n1] * a1 + b1[c];
    hbuf[wid * 2 + 0][c] = h0 > 0.0f ? h0 : 0.0f;
    hbuf[wid * 2 + 1][c] = h1v > 0.0f ? h1v : 0.0f;
    __syncthreads();

    // GEMM2: 256 threads = 8 nodes x 32 outputs -> fp8 store (coalesced 256B/block)
    {
        int w = t >> 5, j = t & 31;
        int n2 = blockIdx.x * 8 + w;
        float dot = 0.0f;
#pragma unroll
        for (int cc = 0; cc < H1; cc++) dot += hbuf[w][cc] * w2s[cc][j];
        y2q[(size_t)n2 * H2 + j] = f2fp8(dinv[n2] * dot);
    }
}

// ---------------- chain-gather layer2 (fp8 via LDS LUT) + ReLU + mean-pool ----------------
// block=256 = 8 half-waves = 8 nodes
__global__ __launch_bounds__(256) void k_agg2_pool(const unsigned char* __restrict__ y2q,
                                                   const int* __restrict__ head,
                                                   const int2* __restrict__ node2,
                                                   const float* __restrict__ dinv,
                                                   const float* __restrict__ b2,
                                                   float* __restrict__ g) {
    __shared__ float lut[256];
    __shared__ float red[256];
    const int t = threadIdx.x;
    lut[t] = fp8lut_val(t);
    __syncthreads();

    const int n = blockIdx.x * 8 + (t >> 5);
    const int c = t & 31;

    float a = lut[y2q[(size_t)n * H2 + c]];  // self-loop
    int e = head[n];
    while (e >= 0) {
        int2 v = node2[e];
        a += lut[y2q[(size_t)v.x * H2 + c]];
        e = v.y;
    }
    float hv = dinv[n] * a + b2[c];
    red[t] = hv > 0.0f ? hv : 0.0f;
    __syncthreads();
    if (t < 128) red[t] += red[t + 128];
    __syncthreads();
    if (t < 64) red[t] += red[t + 64];
    __syncthreads();
    if (t < 32) {
        float s = red[t] + red[t + 32];
        atomicAdd(&g[t], s);
    }
}

__global__ void k_fc(const float* __restrict__ g, const float* __restrict__ Wfc,
                     const float* __restrict__ bfc, float* __restrict__ out) {
    int c = blockIdx.x * 256 + threadIdx.x;
    if (c < C_OUT) {
        const float invn = 1.0f / (float)N_NODES;
        float s = bfc[c];
#pragma unroll
        for (int k = 0; k < H2; k++) s += (g[k] * invn) * Wfc[k * C_OUT + c];
        out[c] = s;
    }
}

extern "C" void kernel_launch(void* const* d_in, const int* in_sizes, int n_in,
                              void* d_out, int out_size, void* d_ws, size_t ws_size,
                              hipStream_t stream) {
    const float* x   = (const float*)d_in[0];
    const int* esrc  = (const int*)d_in[1];
    const int* edst  = (const int*)d_in[2];
    const float* W1  = (const float*)d_in[3];
    const float* b1  = (const float*)d_in[4];
    const float* W2  = (const float*)d_in[5];
    const float* b2  = (const float*)d_in[6];
    const float* Wfc = (const float*)d_in[7];
    const float* bfc = (const float*)d_in[8];
    float* out = (float*)d_out;

    float* ws = (float*)d_ws;
    float* g    = ws + OFF_G;
    float* dinv = ws + OFF_DINV;
    int*   cnt  = (int*)(ws + OFF_CNT);
    int*   head = (int*)(ws + OFF_HEAD);
    int2*  node2 = (int2*)(ws + OFF_NODE2);
    unsigned short* y1b = (unsigned short*)(ws + OFF_Y1B);
    unsigned char*  y2q = (unsigned char*)(ws + OFF_Y2Q);

    const int nb_n = (N_NODES + 255) / 256;  // 391
    const int nb_e = (N_EDGES + 255) / 256;  // 12500

    k_init<<<nb_n, 256, 0, stream>>>(head, cnt, g);
    k_build<<<nb_e, 256, 0, stream>>>(esrc, edst, head, cnt, node2);
    k_dinv<<<nb_n, 256, 0, stream>>>(cnt, dinv);

    k_gemm1<<<(N_NODES + 511) / 512, 256, 0, stream>>>(x, W1, dinv, y1b);
    k_agg1_gemm2<<<N_NODES / 8, 256, 0, stream>>>(y1b, head, node2, dinv, b1, W2, y2q);
    k_agg2_pool<<<N_NODES / 8, 256, 0, stream>>>(y2q, head, node2, dinv, b2, g);

    k_fc<<<(C_OUT + 255) / 256, 256, 0, stream>>>(g, Wfc, bfc, out);
}